// Round 18
// baseline (181.108 us; speedup 1.0000x reference)
//
#include <hip/hip_runtime.h>

// GCN 2-layer — r18 is the SECOND ATTRIBUTION round: identical to r16 except
// setup, partB, and mfma_fused are each launched TWICE (idempotent rewrites).
// dur delta vs r16 (124.6us) = setup + partB + mfma + 3 gaps.
// (r17 measured gather_i8 + gather64 + 2 gaps = 50.8us.)
//   setup  : [partA edge bucketing] + [x->int8 quant] + [W->bf16 W^T]
//   partB  : per bucket: base scan; deg -> rowStart/inv_deg; scatter csr
//   gather_i8   : aggH = bf16(gather_sum(xq*scale))
//   mfma_fused  : h = relu((aggH*inv)@W1+b1) in LDS; y2h = bf16(h@W2)
//   gather64    : out = gather_sum(y2h)*inv + b2

constexpr int NNODES = 50000;
constexpr int NEDGES = 800000;
constexpr int NBUCKETS = (NNODES + 255) / 256;        // 196
constexpr int ABLOCKS = 200;                          // partA workgroups
constexpr int PER = (NEDGES + ABLOCKS - 1) / ABLOCKS; // 4000 edges per WG
constexpr int NB_CAST = NNODES / 16;                  // 3125 (16 rows/block)
constexpr int NB_PREP = (128 * 128 + 64 * 128 + 255) / 256;  // 96

// ---- workspace layout, constexpr cumulative chain (units: 4B words) -------
constexpr size_t SZ_ROWSTART = 50048;                 // needs 50001
constexpr size_t SZ_INVDEG   = 50048;
constexpr size_t SZ_H        = (size_t)ABLOCKS * 256; // 51200
constexpr size_t SZ_LOFS     = (size_t)ABLOCKS * 256;
constexpr size_t SZ_CSR      = NEDGES;
constexpr size_t SZ_TMP      = NEDGES;
constexpr size_t SZ_WT1      = 128 * 128 / 2;         // bf16 -> words
constexpr size_t SZ_WT2      = 64 * 128 / 2;
constexpr size_t SZ_SCALEX   = 50048;
constexpr size_t SZ_XQ       = (size_t)NNODES * 128 / 4;  // int8 -> 1,600,000
constexpr size_t SZ_AGGH     = (size_t)NNODES * 128 / 2;  // bf16 -> 3,200,000
constexpr size_t SZ_Y2H      = (size_t)NNODES * 64 / 2;   // bf16 -> 1,600,000

constexpr size_t OFF_ROWSTART = 0;
constexpr size_t OFF_INVDEG   = OFF_ROWSTART + SZ_ROWSTART;
constexpr size_t OFF_H        = OFF_INVDEG   + SZ_INVDEG;
constexpr size_t OFF_LOFS     = OFF_H        + SZ_H;
constexpr size_t OFF_CSR      = OFF_LOFS     + SZ_LOFS;
constexpr size_t OFF_TMP      = OFF_CSR      + SZ_CSR;
constexpr size_t OFF_WT1      = OFF_TMP      + SZ_TMP;
constexpr size_t OFF_WT2      = OFF_WT1      + SZ_WT1;
constexpr size_t OFF_SCALEX   = OFF_WT2      + SZ_WT2;
constexpr size_t OFF_XQ       = OFF_SCALEX   + SZ_SCALEX;
constexpr size_t OFF_AGGH     = OFF_XQ       + SZ_XQ;
constexpr size_t OFF_Y2H      = OFF_AGGH     + SZ_AGGH;
constexpr size_t WS_WORDS     = OFF_Y2H      + SZ_Y2H;   // 8,264,832 = 33.1 MB
static_assert(WS_WORDS < 11452800, "exceeds r7-proven workspace size");

typedef unsigned short ushortv8 __attribute__((ext_vector_type(8)));
typedef short bf16x8 __attribute__((ext_vector_type(8)));
typedef float f32x4 __attribute__((ext_vector_type(4)));
typedef signed char charv8 __attribute__((ext_vector_type(8)));
typedef signed char charv16 __attribute__((ext_vector_type(16)));

static __device__ __forceinline__ unsigned short f2bf(float f) {
    unsigned u = __float_as_uint(f);
    u += 0x7fff + ((u >> 16) & 1);  // round-to-nearest-even
    return (unsigned short)(u >> 16);
}
static __device__ __forceinline__ float bf2f(unsigned short h) {
    return __uint_as_float((unsigned)h << 16);
}

// ---------------------------------------------------------------------------
// setup: blocks [0,ABLOCKS) partA; [ABLOCKS,+NB_CAST) quantize; rest prep.
// ---------------------------------------------------------------------------
__global__ __launch_bounds__(256) void setup_kernel(
    const int* __restrict__ src, const int* __restrict__ dst,
    unsigned* __restrict__ tmp, int* __restrict__ H, int* __restrict__ LOFS,
    const float* __restrict__ x, signed char* __restrict__ xq,
    float* __restrict__ scaleX,
    const float* __restrict__ W1, const float* __restrict__ W2,
    unsigned short* __restrict__ Wt1, unsigned short* __restrict__ Wt2)
{
    const int blk = blockIdx.x;
    const int t = threadIdx.x;
    if (blk < ABLOCKS) {
        // ----- partA: per-WG bucket partition (LDS hist + scan + cursors) ---
        __shared__ int cnt[256];
        __shared__ int ofs[256];
        __shared__ int cur[256];
        cnt[t] = 0;
        __syncthreads();
        const int lo = blk * PER;
        const int hi = min(lo + PER, NEDGES);
        for (int i = lo + t; i < hi; i += 256)
            atomicAdd(&cnt[dst[i] >> 8], 1);
        __syncthreads();
        ofs[t] = cnt[t];
        __syncthreads();
        #pragma unroll
        for (int off = 1; off < 256; off <<= 1) {
            const int o = (t >= off) ? ofs[t - off] : 0;
            __syncthreads();
            ofs[t] += o;
            __syncthreads();
        }
        const int excl = ofs[t] - cnt[t];
        cur[t] = excl;
        H[blk * 256 + t] = cnt[t];
        LOFS[blk * 256 + t] = excl;
        __syncthreads();
        for (int i = lo + t; i < hi; i += 256) {
            const int d = dst[i];
            const unsigned pk = ((unsigned)src[i] << 8) | (unsigned)(d & 255);
            const int pos = lo + atomicAdd(&cur[d >> 8], 1);
            tmp[pos] = pk;
        }
    } else if (blk < ABLOCKS + NB_CAST) {
        // ----- quantize x -> int8 + per-row scale; 16 lanes/row, 8 elems/lane
        const int lane = t & 63;
        const int wave = t >> 6;
        const int row = (blk - ABLOCKS) * 16 + wave * 4 + (lane >> 4);
        const int ls = lane & 15;
        const float4* px =
            reinterpret_cast<const float4*>(x + (size_t)row * 128 + ls * 8);
        const float4 a = px[0], b = px[1];
        float m = fmaxf(
            fmaxf(fmaxf(fabsf(a.x), fabsf(a.y)), fmaxf(fabsf(a.z), fabsf(a.w))),
            fmaxf(fmaxf(fabsf(b.x), fabsf(b.y)), fmaxf(fabsf(b.z), fabsf(b.w))));
        #pragma unroll
        for (int msk = 1; msk < 16; msk <<= 1)
            m = fmaxf(m, __shfl_xor(m, msk, 16));
        const float rs = (m > 0.f) ? 127.0f / m : 0.f;
        charv8 q;
        q[0] = (signed char)__float2int_rn(a.x * rs);
        q[1] = (signed char)__float2int_rn(a.y * rs);
        q[2] = (signed char)__float2int_rn(a.z * rs);
        q[3] = (signed char)__float2int_rn(a.w * rs);
        q[4] = (signed char)__float2int_rn(b.x * rs);
        q[5] = (signed char)__float2int_rn(b.y * rs);
        q[6] = (signed char)__float2int_rn(b.z * rs);
        q[7] = (signed char)__float2int_rn(b.w * rs);
        *reinterpret_cast<charv8*>(xq + (size_t)row * 128 + ls * 8) = q;
        if (ls == 0) scaleX[row] = (m > 0.f) ? m / 127.0f : 0.f;
    } else {
        // ----- prep: Wt[n][k] = bf16(W[k][n]) -----
        const int i = (blk - ABLOCKS - NB_CAST) * 256 + t;
        if (i < 128 * 128) {
            const int n = i >> 7, k = i & 127;
            Wt1[i] = f2bf(W1[k * 128 + n]);
        } else if (i < 128 * 128 + 64 * 128) {
            const int j = i - 128 * 128;
            const int n = j >> 7, k = j & 127;
            Wt2[j] = f2bf(W2[k * 64 + n]);
        }
    }
}

// ---------------------------------------------------------------------------
// partB: one WG per bucket b. Inline bucket base (column-sum scan of H);
// run-prefix scan; pass1 per-node degree -> rowStart/inv_deg; pass2 scatter.
// ---------------------------------------------------------------------------
__global__ __launch_bounds__(256) void partB_kernel(
    const unsigned* __restrict__ tmp, const int* __restrict__ H,
    const int* __restrict__ LOFS, int* __restrict__ csr,
    int* __restrict__ rowStart, float* __restrict__ inv_deg, int nNodes)
{
    __shared__ int cs[256];    // column sums (bucket totals)
    __shared__ int s[256];     // scan scratch
    __shared__ int epfx[256];  // exclusive run prefix for this bucket
    __shared__ int base[256];  // run base addr in tmp
    __shared__ int cnt[256];
    __shared__ int fill[256];
    const int b = blockIdx.x;
    const int t = threadIdx.x;

    int sum = 0;
    for (int w = 0; w < ABLOCKS; ++w) sum += H[w * 256 + t];
    cs[t] = sum;
    s[t] = sum;
    __syncthreads();
    #pragma unroll
    for (int off = 1; off < 256; off <<= 1) {
        const int o = (t >= off) ? s[t - off] : 0;
        __syncthreads();
        s[t] += o;
        __syncthreads();
    }
    const int gbase = s[b] - cs[b];  // exclusive prefix at bucket b
    const int total = cs[b];
    __syncthreads();  // all threads read s[b] before s is reused

    const int hv = (t < ABLOCKS) ? H[t * 256 + b] : 0;
    s[t] = hv;
    if (t < ABLOCKS) base[t] = t * PER + LOFS[t * 256 + b];
    cnt[t] = 0;
    __syncthreads();
    #pragma unroll
    for (int off = 1; off < 256; off <<= 1) {
        const int o = (t >= off) ? s[t - off] : 0;
        __syncthreads();
        s[t] += o;
        __syncthreads();
    }
    epfx[t] = s[t] - hv;
    __syncthreads();

    // pass 1: per-node degree
    for (int j = t; j < total; j += 256) {
        int loW = 0, hiW = ABLOCKS;
        while (hiW - loW > 1) {
            const int mid = (loW + hiW) >> 1;
            if (epfx[mid] <= j) loW = mid; else hiW = mid;
        }
        const unsigned p = tmp[base[loW] + (j - epfx[loW])];
        atomicAdd(&cnt[p & 255u], 1);
    }
    __syncthreads();
    s[t] = cnt[t];
    __syncthreads();
    #pragma unroll
    for (int off = 1; off < 256; off <<= 1) {
        const int o = (t >= off) ? s[t - off] : 0;
        __syncthreads();
        s[t] += o;
        __syncthreads();
    }
    const int excl = gbase + s[t] - cnt[t];
    const int node = b * 256 + t;
    if (node < nNodes) {
        rowStart[node] = excl;
        inv_deg[node] = 1.0f / fmaxf((float)cnt[t], 1.0f);
    }
    if (b == 0 && t == 0) rowStart[nNodes] = NEDGES;
    fill[t] = excl;
    __syncthreads();

    // pass 2: scatter
    for (int j = t; j < total; j += 256) {
        int loW = 0, hiW = ABLOCKS;
        while (hiW - loW > 1) {
            const int mid = (loW + hiW) >> 1;
            if (epfx[mid] <= j) loW = mid; else hiW = mid;
        }
        const unsigned p = tmp[base[loW] + (j - epfx[loW])];
        const int pos = atomicAdd(&fill[p & 255u], 1);
        csr[pos] = (int)(p >> 8);
    }
}

// ---------------------------------------------------------------------------
// int8-row gather-aggregate (layer 1). One wave per dst node; 64 lanes =
// 8 edge-slots x 8 lanes/row (16B = 16 int8 elems/lane, coalesced 128B rows).
// ---------------------------------------------------------------------------
__global__ __launch_bounds__(256) void gather_i8_kernel(
    const charv16* __restrict__ featq, const float* __restrict__ scaleX,
    const int* __restrict__ csr, const int* __restrict__ rowStart,
    ushortv8* __restrict__ aggH, int nNodes)
{
    constexpr int LPR = 8;   // lanes per row
    constexpr int EPW = 8;   // parallel edges per wave
    const int wid = (blockIdx.x * 256 + threadIdx.x) >> 6;
    if (wid >= nNodes) return;
    const int lane = threadIdx.x & 63;
    const int eslot = lane / LPR;
    const int cg = lane % LPR;   // 16-elem chunk index within row
    const int rs = rowStart[wid];
    const int re = rowStart[wid + 1];

    float acc0[16] = {}, acc1[16] = {};
    int j = rs + eslot;
    for (; j + EPW < re; j += 2 * EPW) {
        const int s0 = csr[j];
        const int s1 = csr[j + EPW];
        const charv16 q0 = featq[(size_t)s0 * 8 + cg];
        const charv16 q1 = featq[(size_t)s1 * 8 + cg];
        const float sc0 = scaleX[s0];
        const float sc1 = scaleX[s1];
        #pragma unroll
        for (int t = 0; t < 16; ++t) acc0[t] += (float)q0[t] * sc0;
        #pragma unroll
        for (int t = 0; t < 16; ++t) acc1[t] += (float)q1[t] * sc1;
    }
    if (j < re) {
        const int s0 = csr[j];
        const charv16 q0 = featq[(size_t)s0 * 8 + cg];
        const float sc0 = scaleX[s0];
        #pragma unroll
        for (int t = 0; t < 16; ++t) acc0[t] += (float)q0[t] * sc0;
    }
    #pragma unroll
    for (int t = 0; t < 16; ++t) acc0[t] += acc1[t];

    #pragma unroll
    for (int off = LPR; off < 64; off <<= 1) {
        #pragma unroll
        for (int t = 0; t < 16; ++t) acc0[t] += __shfl_down(acc0[t], off, 64);
    }

    if (lane < LPR) {
        ushortv8 o0, o1;
        #pragma unroll
        for (int t = 0; t < 8; ++t) {
            o0[t] = f2bf(acc0[t]);
            o1[t] = f2bf(acc0[t + 8]);
        }
        aggH[(size_t)wid * 16 + cg * 2] = o0;
        aggH[(size_t)wid * 16 + cg * 2 + 1] = o1;
    }
}

// ---------------------------------------------------------------------------
// bf16-row gather-aggregate (layer 2, r13-proven shape, DEPTH=2).
// ---------------------------------------------------------------------------
template<int F, bool EPI>
__global__ __launch_bounds__(256) void gather_bf16_kernel(
    const ushortv8* __restrict__ feat, const int* __restrict__ csr,
    const int* __restrict__ rowStart, const float* __restrict__ inv_deg,
    const float* __restrict__ bias, float* __restrict__ outv, int nNodes)
{
    constexpr int LPR = F / 8;     // lanes per row: 8 (F=64)
    constexpr int EPW = 64 / LPR;  // parallel edges per wave: 8
    const int wid = (blockIdx.x * 256 + threadIdx.x) >> 6;
    if (wid >= nNodes) return;
    const int lane = threadIdx.x & 63;
    const int eslot = lane / LPR;
    const int cg = lane % LPR;
    const int rs = rowStart[wid];
    const int re = rowStart[wid + 1];

    float acc0[8] = {}, acc1[8] = {};
    int j = rs + eslot;
    for (; j + EPW < re; j += 2 * EPW) {
        const int s0 = csr[j];
        const int s1 = csr[j + EPW];
        const ushortv8 v0 = feat[(size_t)s0 * LPR + cg];
        const ushortv8 v1 = feat[(size_t)s1 * LPR + cg];
        #pragma unroll
        for (int t = 0; t < 8; ++t) acc0[t] += bf2f(v0[t]);
        #pragma unroll
        for (int t = 0; t < 8; ++t) acc1[t] += bf2f(v1[t]);
    }
    if (j < re) {
        const int s0 = csr[j];
        const ushortv8 v0 = feat[(size_t)s0 * LPR + cg];
        #pragma unroll
        for (int t = 0; t < 8; ++t) acc0[t] += bf2f(v0[t]);
    }
    #pragma unroll
    for (int t = 0; t < 8; ++t) acc0[t] += acc1[t];

    #pragma unroll
    for (int off = LPR; off < 64; off <<= 1) {
        #pragma unroll
        for (int t = 0; t < 8; ++t) acc0[t] += __shfl_down(acc0[t], off, 64);
    }

    if (lane < LPR) {
        if constexpr (EPI) {
            const float s = inv_deg[wid];
            #pragma unroll
            for (int t = 0; t < 8; ++t) acc0[t] = acc0[t] * s + bias[cg * 8 + t];
        }
        float* o = outv + (size_t)wid * F + cg * 8;
        *reinterpret_cast<float4*>(o) =
            make_float4(acc0[0], acc0[1], acc0[2], acc0[3]);
        *reinterpret_cast<float4*>(o + 4) =
            make_float4(acc0[4], acc0[5], acc0[6], acc0[7]);
    }
}

// ---------------------------------------------------------------------------
// Fused MFMA GEMMs, K=128, block = 4 waves = 64 rows (unchanged, proven r13):
//   h = relu((A*inv_deg)@Wt1^T + b1)   -> bf16, kept in LDS (la)
//   y2h = bf16(h@Wt2^T)                -> global
// ---------------------------------------------------------------------------
__global__ __launch_bounds__(256) void mfma_fused_kernel(
    const ushortv8* __restrict__ A,      // aggH bf16 [nrows][16 chunks]
    const float* __restrict__ inv_deg,
    const ushortv8* __restrict__ Wt1,    // bf16 [128][16 chunks]
    const float* __restrict__ b1,
    const ushortv8* __restrict__ Wt2,    // bf16 [64][16 chunks]
    unsigned short* __restrict__ y2h,    // bf16 [nrows][64]
    int nrows)
{
    constexpr int LDK = 136;  // +8 bf16 pad
    __shared__ alignas(16) unsigned short lwt1[128][LDK];
    __shared__ alignas(16) unsigned short lwt2[64][LDK];
    __shared__ alignas(16) unsigned short la[64][LDK];

    const int row0 = blockIdx.x * 64;
    const int t = threadIdx.x;

    for (int i = t; i < 128 * 16; i += 256) {
        const int r = i >> 4, c = i & 15;
        *reinterpret_cast<ushortv8*>(&lwt1[r][c * 8]) = Wt1[i];
    }
    for (int i = t; i < 64 * 16; i += 256) {
        const int r = i >> 4, c = i & 15;
        *reinterpret_cast<ushortv8*>(&lwt2[r][c * 8]) = Wt2[i];
    }
    for (int i = t; i < 64 * 16; i += 256) {
        const int r = i >> 4, c = i & 15;
        const int row = row0 + r;
        ushortv8 v = {};
        if (row < nrows) {
            v = A[(size_t)row * 16 + c];
            const float s = inv_deg[row];
            #pragma unroll
            for (int jj = 0; jj < 8; ++jj) v[jj] = f2bf(bf2f(v[jj]) * s);
        }
        *reinterpret_cast<ushortv8*>(&la[r][c * 8]) = v;
    }
    __syncthreads();

    const int wave = t >> 6, lane = t & 63;
    const int m = lane & 15, kg = lane >> 4;  // k-group 0..3

    // GEMM1: 64x128 = (64x128) @ (128x128)
    f32x4 acc1[8] = {};
    #pragma unroll
    for (int kk = 0; kk < 4; ++kk) {
        const bf16x8 af =
            *reinterpret_cast<const bf16x8*>(&la[wave * 16 + m][kk * 32 + kg * 8]);
        #pragma unroll
        for (int n = 0; n < 8; ++n) {
            const bf16x8 bf =
                *reinterpret_cast<const bf16x8*>(&lwt1[n * 16 + m][kk * 32 + kg * 8]);
            acc1[n] = __builtin_amdgcn_mfma_f32_16x16x32_bf16(af, bf, acc1[n], 0, 0, 0);
        }
    }
    // epilogue1: h = bf16(relu(acc+b1)) into own la rows
    #pragma unroll
    for (int n = 0; n < 8; ++n) {
        const float bv = b1[n * 16 + m];
        #pragma unroll
        for (int q = 0; q < 4; ++q) {
            const int r = wave * 16 + kg * 4 + q;
            la[r][n * 16 + m] = f2bf(fmaxf(acc1[n][q] + bv, 0.f));
        }
    }
    __syncthreads();  // order h ds_writes before GEMM2 ds_reads

    // GEMM2: 64x64 = (64x128) @ (128x64)
    f32x4 acc2[4] = {};
    #pragma unroll
    for (int kk = 0; kk < 4; ++kk) {
        const bf16x8 af =
            *reinterpret_cast<const bf16x8*>(&la[wave * 16 + m][kk * 32 + kg * 8]);
        #pragma unroll
        for (int n = 0; n < 4; ++n) {
            const bf16x8 bf =
                *reinterpret_cast<const bf16x8*>(&lwt2[n * 16 + m][kk * 32 + kg * 8]);
            acc2[n] = __builtin_amdgcn_mfma_f32_16x16x32_bf16(af, bf, acc2[n], 0, 0, 0);
        }
    }
    __syncthreads();  // all GEMM2 reads of la complete before epilogue2 rewrites it
    // epilogue2: stage y2h bf16 into own la rows (cols 0..63)
    #pragma unroll
    for (int n = 0; n < 4; ++n) {
        #pragma unroll
        for (int q = 0; q < 4; ++q) {
            const int r = wave * 16 + kg * 4 + q;
            la[r][n * 16 + m] = f2bf(acc2[n][q]);
        }
    }
    __syncthreads();
    for (int i = t; i < 64 * 8; i += 256) {
        const int r = i >> 3, c = i & 7;
        const int row = row0 + r;
        if (row < nrows)
            *reinterpret_cast<ushortv8*>(&y2h[(size_t)row * 64 + c * 8]) =
                *reinterpret_cast<const ushortv8*>(&la[r][c * 8]);
    }
}

// ---------------------------------------------------------------------------
extern "C" void kernel_launch(void* const* d_in, const int* in_sizes, int n_in,
                              void* d_out, int out_size, void* d_ws, size_t ws_size,
                              hipStream_t stream)
{
    const float* x   = (const float*)d_in[0];
    const int*   src = (const int*)d_in[1];
    const int*   dst = (const int*)d_in[2];
    const float* W1  = (const float*)d_in[3];
    const float* b1  = (const float*)d_in[4];
    const float* W2  = (const float*)d_in[5];
    const float* b2  = (const float*)d_in[6];
    float* out = (float*)d_out;

    float* ws  = (float*)d_ws;
    int*   wsi = (int*)d_ws;
    int*            rowStart = wsi + OFF_ROWSTART;
    float*          invdeg   = ws  + OFF_INVDEG;
    int*            H        = wsi + OFF_H;
    int*            LOFS     = wsi + OFF_LOFS;
    int*            csr      = wsi + OFF_CSR;
    unsigned*       tmp      = (unsigned*)(wsi + OFF_TMP);
    unsigned short* Wt1      = (unsigned short*)(wsi + OFF_WT1);
    unsigned short* Wt2      = (unsigned short*)(wsi + OFF_WT2);
    float*          scaleX   = ws  + OFF_SCALEX;
    signed char*    xq       = (signed char*)(wsi + OFF_XQ);
    ushortv8*       aggH     = (ushortv8*)(wsi + OFF_AGGH);
    unsigned short* y2h      = (unsigned short*)(wsi + OFF_Y2H);

    // 1) partA + int8 quantize + W prep  [x2: attribution probe, idempotent]
    setup_kernel<<<ABLOCKS + NB_CAST + NB_PREP, 256, 0, stream>>>(
        src, dst, tmp, H, LOFS, x, xq, scaleX, W1, W2, Wt1, Wt2);
    setup_kernel<<<ABLOCKS + NB_CAST + NB_PREP, 256, 0, stream>>>(
        src, dst, tmp, H, LOFS, x, xq, scaleX, W1, W2, Wt1, Wt2);

    // 2) CSR finalize per bucket  [x2: attribution probe, idempotent]
    partB_kernel<<<NBUCKETS, 256, 0, stream>>>(
        tmp, H, LOFS, csr, rowStart, invdeg, NNODES);
    partB_kernel<<<NBUCKETS, 256, 0, stream>>>(
        tmp, H, LOFS, csr, rowStart, invdeg, NNODES);

    // 3) layer-1 aggregate -> bf16 aggH
    gather_i8_kernel<<<(NNODES + 3) / 4, 256, 0, stream>>>(
        (const charv16*)xq, scaleX, csr, rowStart, aggH, NNODES);

    // 4) fused GEMM1+GEMM2 -> y2h  [x2: attribution probe, idempotent]
    mfma_fused_kernel<<<(NNODES + 63) / 64, 256, 0, stream>>>(
        aggH, invdeg, (const ushortv8*)Wt1, b1, (const ushortv8*)Wt2,
        y2h, NNODES);
    mfma_fused_kernel<<<(NNODES + 63) / 64, 256, 0, stream>>>(
        aggH, invdeg, (const ushortv8*)Wt1, b1, (const ushortv8*)Wt2,
        y2h, NNODES);

    // 5) layer-2 aggregate + scale + bias -> out
    gather_bf16_kernel<64, true><<<(NNODES + 3) / 4, 256, 0, stream>>>(
        (const ushortv8*)y2h, csr, rowStart, invdeg, b2, out, NNODES);
}

// Round 19
// 149.431 us; speedup vs baseline: 1.2120x; 1.2120x over previous
//
#include <hip/hip_runtime.h>

// GCN 2-layer, 4 launches (r19: gather_i8 + mfma fused; aggH eliminated):
//   setup   : [partA edge bucketing] + [x->int8 quant] + [W->bf16 W^T]
//   partB   : per bucket: base scan; deg -> rowStart/inv_deg; scatter csr
//   gat_gemm: per 64-node block: phase1 = per-wave edge-gather of int8 rows
//             -> inv_deg-scaled bf16 row straight into LDS 'la';
//             phase2 = GEMM1(relu,b1)+GEMM2 with Wt read from global (L2-hot)
//             -> y2h. (Weights NOT LDS-staged: keeps LDS at 17.4KB so the
//             latency-bound gather phase keeps ~20 waves/CU of TLP.)
//   gather64: out = gather_sum(y2h)*inv + b2
// r17/r18 attribution: kernels ~92us, gaps ~3-4us each, fixed replay ~17us.
// This round removes 1 launch+gap and the 25.6MB aggH L2 round-trip.

constexpr int NNODES = 50000;
constexpr int NEDGES = 800000;
constexpr int NBUCKETS = (NNODES + 255) / 256;        // 196
constexpr int ABLOCKS = 200;                          // partA workgroups
constexpr int PER = (NEDGES + ABLOCKS - 1) / ABLOCKS; // 4000 edges per WG
constexpr int NB_CAST = NNODES / 16;                  // 3125 (16 rows/block)
constexpr int NB_PREP = (128 * 128 + 64 * 128 + 255) / 256;  // 96

// ---- workspace layout, constexpr cumulative chain (units: 4B words) -------
constexpr size_t SZ_ROWSTART = 50048;                 // needs 50001
constexpr size_t SZ_INVDEG   = 50048;
constexpr size_t SZ_H        = (size_t)ABLOCKS * 256; // 51200
constexpr size_t SZ_LOFS     = (size_t)ABLOCKS * 256;
constexpr size_t SZ_CSR      = NEDGES;
constexpr size_t SZ_TMP      = NEDGES;
constexpr size_t SZ_WT1      = 128 * 128 / 2;         // bf16 -> words
constexpr size_t SZ_WT2      = 64 * 128 / 2;
constexpr size_t SZ_SCALEX   = 50048;
constexpr size_t SZ_XQ       = (size_t)NNODES * 128 / 4;  // int8 -> 1,600,000
constexpr size_t SZ_Y2H      = (size_t)NNODES * 64 / 2;   // bf16 -> 1,600,000

constexpr size_t OFF_ROWSTART = 0;
constexpr size_t OFF_INVDEG   = OFF_ROWSTART + SZ_ROWSTART;
constexpr size_t OFF_H        = OFF_INVDEG   + SZ_INVDEG;
constexpr size_t OFF_LOFS     = OFF_H        + SZ_H;
constexpr size_t OFF_CSR      = OFF_LOFS     + SZ_LOFS;
constexpr size_t OFF_TMP      = OFF_CSR      + SZ_CSR;
constexpr size_t OFF_WT1      = OFF_TMP      + SZ_TMP;
constexpr size_t OFF_WT2      = OFF_WT1      + SZ_WT1;
constexpr size_t OFF_SCALEX   = OFF_WT2      + SZ_WT2;
constexpr size_t OFF_XQ       = OFF_SCALEX   + SZ_SCALEX;
constexpr size_t OFF_Y2H      = OFF_XQ       + SZ_XQ;
constexpr size_t WS_WORDS     = OFF_Y2H      + SZ_Y2H;   // 5,064,832 = 20.3 MB
static_assert(WS_WORDS < 11452800, "exceeds r7-proven workspace size");

typedef unsigned short ushortv8 __attribute__((ext_vector_type(8)));
typedef short bf16x8 __attribute__((ext_vector_type(8)));
typedef float f32x4 __attribute__((ext_vector_type(4)));
typedef signed char charv8 __attribute__((ext_vector_type(8)));
typedef signed char charv16 __attribute__((ext_vector_type(16)));

static __device__ __forceinline__ unsigned short f2bf(float f) {
    unsigned u = __float_as_uint(f);
    u += 0x7fff + ((u >> 16) & 1);  // round-to-nearest-even
    return (unsigned short)(u >> 16);
}
static __device__ __forceinline__ float bf2f(unsigned short h) {
    return __uint_as_float((unsigned)h << 16);
}

// ---------------------------------------------------------------------------
// setup: blocks [0,ABLOCKS) partA; [ABLOCKS,+NB_CAST) quantize; rest prep.
// ---------------------------------------------------------------------------
__global__ __launch_bounds__(256) void setup_kernel(
    const int* __restrict__ src, const int* __restrict__ dst,
    unsigned* __restrict__ tmp, int* __restrict__ H, int* __restrict__ LOFS,
    const float* __restrict__ x, signed char* __restrict__ xq,
    float* __restrict__ scaleX,
    const float* __restrict__ W1, const float* __restrict__ W2,
    unsigned short* __restrict__ Wt1, unsigned short* __restrict__ Wt2)
{
    const int blk = blockIdx.x;
    const int t = threadIdx.x;
    if (blk < ABLOCKS) {
        // ----- partA: per-WG bucket partition (LDS hist + scan + cursors) ---
        __shared__ int cnt[256];
        __shared__ int ofs[256];
        __shared__ int cur[256];
        cnt[t] = 0;
        __syncthreads();
        const int lo = blk * PER;
        const int hi = min(lo + PER, NEDGES);
        for (int i = lo + t; i < hi; i += 256)
            atomicAdd(&cnt[dst[i] >> 8], 1);
        __syncthreads();
        ofs[t] = cnt[t];
        __syncthreads();
        #pragma unroll
        for (int off = 1; off < 256; off <<= 1) {
            const int o = (t >= off) ? ofs[t - off] : 0;
            __syncthreads();
            ofs[t] += o;
            __syncthreads();
        }
        const int excl = ofs[t] - cnt[t];
        cur[t] = excl;
        H[blk * 256 + t] = cnt[t];
        LOFS[blk * 256 + t] = excl;
        __syncthreads();
        for (int i = lo + t; i < hi; i += 256) {
            const int d = dst[i];
            const unsigned pk = ((unsigned)src[i] << 8) | (unsigned)(d & 255);
            const int pos = lo + atomicAdd(&cur[d >> 8], 1);
            tmp[pos] = pk;
        }
    } else if (blk < ABLOCKS + NB_CAST) {
        // ----- quantize x -> int8 + per-row scale; 16 lanes/row, 8 elems/lane
        const int lane = t & 63;
        const int wave = t >> 6;
        const int row = (blk - ABLOCKS) * 16 + wave * 4 + (lane >> 4);
        const int ls = lane & 15;
        const float4* px =
            reinterpret_cast<const float4*>(x + (size_t)row * 128 + ls * 8);
        const float4 a = px[0], b = px[1];
        float m = fmaxf(
            fmaxf(fmaxf(fabsf(a.x), fabsf(a.y)), fmaxf(fabsf(a.z), fabsf(a.w))),
            fmaxf(fmaxf(fabsf(b.x), fabsf(b.y)), fmaxf(fabsf(b.z), fabsf(b.w))));
        #pragma unroll
        for (int msk = 1; msk < 16; msk <<= 1)
            m = fmaxf(m, __shfl_xor(m, msk, 16));
        const float rs = (m > 0.f) ? 127.0f / m : 0.f;
        charv8 q;
        q[0] = (signed char)__float2int_rn(a.x * rs);
        q[1] = (signed char)__float2int_rn(a.y * rs);
        q[2] = (signed char)__float2int_rn(a.z * rs);
        q[3] = (signed char)__float2int_rn(a.w * rs);
        q[4] = (signed char)__float2int_rn(b.x * rs);
        q[5] = (signed char)__float2int_rn(b.y * rs);
        q[6] = (signed char)__float2int_rn(b.z * rs);
        q[7] = (signed char)__float2int_rn(b.w * rs);
        *reinterpret_cast<charv8*>(xq + (size_t)row * 128 + ls * 8) = q;
        if (ls == 0) scaleX[row] = (m > 0.f) ? m / 127.0f : 0.f;
    } else {
        // ----- prep: Wt[n][k] = bf16(W[k][n]) -----
        const int i = (blk - ABLOCKS - NB_CAST) * 256 + t;
        if (i < 128 * 128) {
            const int n = i >> 7, k = i & 127;
            Wt1[i] = f2bf(W1[k * 128 + n]);
        } else if (i < 128 * 128 + 64 * 128) {
            const int j = i - 128 * 128;
            const int n = j >> 7, k = j & 127;
            Wt2[j] = f2bf(W2[k * 64 + n]);
        }
    }
}

// ---------------------------------------------------------------------------
// partB: one WG per bucket b. Inline bucket base (column-sum scan of H);
// run-prefix scan; pass1 per-node degree -> rowStart/inv_deg; pass2 scatter.
// ---------------------------------------------------------------------------
__global__ __launch_bounds__(256) void partB_kernel(
    const unsigned* __restrict__ tmp, const int* __restrict__ H,
    const int* __restrict__ LOFS, int* __restrict__ csr,
    int* __restrict__ rowStart, float* __restrict__ inv_deg, int nNodes)
{
    __shared__ int cs[256];    // column sums (bucket totals)
    __shared__ int s[256];     // scan scratch
    __shared__ int epfx[256];  // exclusive run prefix for this bucket
    __shared__ int base[256];  // run base addr in tmp
    __shared__ int cnt[256];
    __shared__ int fill[256];
    const int b = blockIdx.x;
    const int t = threadIdx.x;

    int sum = 0;
    for (int w = 0; w < ABLOCKS; ++w) sum += H[w * 256 + t];
    cs[t] = sum;
    s[t] = sum;
    __syncthreads();
    #pragma unroll
    for (int off = 1; off < 256; off <<= 1) {
        const int o = (t >= off) ? s[t - off] : 0;
        __syncthreads();
        s[t] += o;
        __syncthreads();
    }
    const int gbase = s[b] - cs[b];  // exclusive prefix at bucket b
    const int total = cs[b];
    __syncthreads();  // all threads read s[b] before s is reused

    const int hv = (t < ABLOCKS) ? H[t * 256 + b] : 0;
    s[t] = hv;
    if (t < ABLOCKS) base[t] = t * PER + LOFS[t * 256 + b];
    cnt[t] = 0;
    __syncthreads();
    #pragma unroll
    for (int off = 1; off < 256; off <<= 1) {
        const int o = (t >= off) ? s[t - off] : 0;
        __syncthreads();
        s[t] += o;
        __syncthreads();
    }
    epfx[t] = s[t] - hv;
    __syncthreads();

    // pass 1: per-node degree
    for (int j = t; j < total; j += 256) {
        int loW = 0, hiW = ABLOCKS;
        while (hiW - loW > 1) {
            const int mid = (loW + hiW) >> 1;
            if (epfx[mid] <= j) loW = mid; else hiW = mid;
        }
        const unsigned p = tmp[base[loW] + (j - epfx[loW])];
        atomicAdd(&cnt[p & 255u], 1);
    }
    __syncthreads();
    s[t] = cnt[t];
    __syncthreads();
    #pragma unroll
    for (int off = 1; off < 256; off <<= 1) {
        const int o = (t >= off) ? s[t - off] : 0;
        __syncthreads();
        s[t] += o;
        __syncthreads();
    }
    const int excl = gbase + s[t] - cnt[t];
    const int node = b * 256 + t;
    if (node < nNodes) {
        rowStart[node] = excl;
        inv_deg[node] = 1.0f / fmaxf((float)cnt[t], 1.0f);
    }
    if (b == 0 && t == 0) rowStart[nNodes] = NEDGES;
    fill[t] = excl;
    __syncthreads();

    // pass 2: scatter
    for (int j = t; j < total; j += 256) {
        int loW = 0, hiW = ABLOCKS;
        while (hiW - loW > 1) {
            const int mid = (loW + hiW) >> 1;
            if (epfx[mid] <= j) loW = mid; else hiW = mid;
        }
        const unsigned p = tmp[base[loW] + (j - epfx[loW])];
        const int pos = atomicAdd(&fill[p & 255u], 1);
        csr[pos] = (int)(p >> 8);
    }
}

// ---------------------------------------------------------------------------
// Fused gather(int8) + GEMM1(relu,b1) + GEMM2. Block = 64 nodes, 4 waves.
// Phase 1 (16 passes): wave w, pass p gathers node row0+p*4+w (r16 gather_i8
// inner loop: 8 edge-slots x 8 lanes x 16 int8/lane, fp32 accum, shuffle
// reduce) -> lanes 0-7 write bf16(sum*inv_deg) into la[p*4+w][*].
// Phase 2: r13 GEMM structure; Wt1/Wt2/b1 read from GLOBAL (all blocks read
// the same 48KB -> L1/L2-hot broadcast; keeps LDS at 17.4KB for occupancy).
// Barriers: after phase1 (cross-wave la); between epi1 and GEMM2 (r12 lesson:
// ds-write->ds-read with no data dep can be scheduler-reordered); after GEMM2
// (la reuse); after epi2 (cooperative store).
// ---------------------------------------------------------------------------
__global__ __launch_bounds__(256) void gat_gemm_kernel(
    const charv16* __restrict__ featq, const float* __restrict__ scaleX,
    const int* __restrict__ csr, const int* __restrict__ rowStart,
    const float* __restrict__ inv_deg,
    const unsigned short* __restrict__ Wt1,  // bf16 [128][128]
    const float* __restrict__ b1,
    const unsigned short* __restrict__ Wt2,  // bf16 [64][128]
    unsigned short* __restrict__ y2h,        // bf16 [nrows][64]
    int nNodes)
{
    constexpr int LDK = 136;  // +8 bf16 pad
    __shared__ alignas(16) unsigned short la[64][LDK];

    const int row0 = blockIdx.x * 64;
    const int t = threadIdx.x;
    const int wave = t >> 6, lane = t & 63;

    // ---------------- phase 1: gather 64 nodes (16 passes x 4 waves) -------
    const int eslot = lane >> 3;   // 0..7
    const int cg = lane & 7;       // 16-elem chunk within row
    for (int p = 0; p < 16; ++p) {
        const int r = p * 4 + wave;
        const int node = row0 + r;
        float acc0[16] = {}, acc1[16] = {};
        if (node < nNodes) {
            const int rs = rowStart[node];
            const int re = rowStart[node + 1];
            int j = rs + eslot;
            for (; j + 8 < re; j += 16) {
                const int s0 = csr[j];
                const int s1 = csr[j + 8];
                const charv16 q0 = featq[(size_t)s0 * 8 + cg];
                const charv16 q1 = featq[(size_t)s1 * 8 + cg];
                const float sc0 = scaleX[s0];
                const float sc1 = scaleX[s1];
                #pragma unroll
                for (int k = 0; k < 16; ++k) acc0[k] += (float)q0[k] * sc0;
                #pragma unroll
                for (int k = 0; k < 16; ++k) acc1[k] += (float)q1[k] * sc1;
            }
            if (j < re) {
                const int s0 = csr[j];
                const charv16 q0 = featq[(size_t)s0 * 8 + cg];
                const float sc0 = scaleX[s0];
                #pragma unroll
                for (int k = 0; k < 16; ++k) acc0[k] += (float)q0[k] * sc0;
            }
        }
        #pragma unroll
        for (int k = 0; k < 16; ++k) acc0[k] += acc1[k];
        #pragma unroll
        for (int off = 8; off < 64; off <<= 1) {
            #pragma unroll
            for (int k = 0; k < 16; ++k)
                acc0[k] += __shfl_down(acc0[k], off, 64);
        }
        if (lane < 8) {
            const float s = (node < nNodes) ? inv_deg[node] : 0.f;
            ushortv8 o0, o1;
            #pragma unroll
            for (int k = 0; k < 8; ++k) {
                o0[k] = f2bf(acc0[k] * s);
                o1[k] = f2bf(acc0[k + 8] * s);
            }
            *reinterpret_cast<ushortv8*>(&la[r][cg * 16]) = o0;
            *reinterpret_cast<ushortv8*>(&la[r][cg * 16 + 8]) = o1;
        }
    }
    __syncthreads();

    // ---------------- phase 2: GEMM1 + GEMM2 (Wt from global) --------------
    const int m = lane & 15, kg = lane >> 4;  // k-group 0..3

    f32x4 acc1g[8] = {};
    #pragma unroll
    for (int kk = 0; kk < 4; ++kk) {
        const bf16x8 af =
            *reinterpret_cast<const bf16x8*>(&la[wave * 16 + m][kk * 32 + kg * 8]);
        #pragma unroll
        for (int n = 0; n < 8; ++n) {
            const bf16x8 bf = *reinterpret_cast<const bf16x8*>(
                &Wt1[((size_t)(n * 16 + m) << 7) + kk * 32 + kg * 8]);
            acc1g[n] = __builtin_amdgcn_mfma_f32_16x16x32_bf16(af, bf, acc1g[n], 0, 0, 0);
        }
    }
    // epilogue1: h = bf16(relu(acc+b1)) into own la rows
    #pragma unroll
    for (int n = 0; n < 8; ++n) {
        const float bv = b1[n * 16 + m];
        #pragma unroll
        for (int q = 0; q < 4; ++q) {
            const int r = wave * 16 + kg * 4 + q;
            la[r][n * 16 + m] = f2bf(fmaxf(acc1g[n][q] + bv, 0.f));
        }
    }
    __syncthreads();  // order h ds_writes before GEMM2 ds_reads (r12 lesson)

    f32x4 acc2g[4] = {};
    #pragma unroll
    for (int kk = 0; kk < 4; ++kk) {
        const bf16x8 af =
            *reinterpret_cast<const bf16x8*>(&la[wave * 16 + m][kk * 32 + kg * 8]);
        #pragma unroll
        for (int n = 0; n < 4; ++n) {
            const bf16x8 bf = *reinterpret_cast<const bf16x8*>(
                &Wt2[((size_t)(n * 16 + m) << 7) + kk * 32 + kg * 8]);
            acc2g[n] = __builtin_amdgcn_mfma_f32_16x16x32_bf16(af, bf, acc2g[n], 0, 0, 0);
        }
    }
    __syncthreads();  // all GEMM2 reads of la done before epilogue2 rewrites
    #pragma unroll
    for (int n = 0; n < 4; ++n) {
        #pragma unroll
        for (int q = 0; q < 4; ++q) {
            const int r = wave * 16 + kg * 4 + q;
            la[r][n * 16 + m] = f2bf(acc2g[n][q]);
        }
    }
    __syncthreads();
    for (int i = t; i < 64 * 8; i += 256) {
        const int r = i >> 3, c = i & 7;
        const int row = row0 + r;
        if (row < nNodes)
            *reinterpret_cast<ushortv8*>(&y2h[(size_t)row * 64 + c * 8]) =
                *reinterpret_cast<const ushortv8*>(&la[r][c * 8]);
    }
}

// ---------------------------------------------------------------------------
// bf16-row gather-aggregate (layer 2, r13-proven shape, DEPTH=2).
// ---------------------------------------------------------------------------
template<int F, bool EPI>
__global__ __launch_bounds__(256) void gather_bf16_kernel(
    const ushortv8* __restrict__ feat, const int* __restrict__ csr,
    const int* __restrict__ rowStart, const float* __restrict__ inv_deg,
    const float* __restrict__ bias, float* __restrict__ outv, int nNodes)
{
    constexpr int LPR = F / 8;     // lanes per row: 8 (F=64)
    constexpr int EPW = 64 / LPR;  // parallel edges per wave: 8
    const int wid = (blockIdx.x * 256 + threadIdx.x) >> 6;
    if (wid >= nNodes) return;
    const int lane = threadIdx.x & 63;
    const int eslot = lane / LPR;
    const int cg = lane % LPR;
    const int rs = rowStart[wid];
    const int re = rowStart[wid + 1];

    float acc0[8] = {}, acc1[8] = {};
    int j = rs + eslot;
    for (; j + EPW < re; j += 2 * EPW) {
        const int s0 = csr[j];
        const int s1 = csr[j + EPW];
        const ushortv8 v0 = feat[(size_t)s0 * LPR + cg];
        const ushortv8 v1 = feat[(size_t)s1 * LPR + cg];
        #pragma unroll
        for (int t = 0; t < 8; ++t) acc0[t] += bf2f(v0[t]);
        #pragma unroll
        for (int t = 0; t < 8; ++t) acc1[t] += bf2f(v1[t]);
    }
    if (j < re) {
        const int s0 = csr[j];
        const ushortv8 v0 = feat[(size_t)s0 * LPR + cg];
        #pragma unroll
        for (int t = 0; t < 8; ++t) acc0[t] += bf2f(v0[t]);
    }
    #pragma unroll
    for (int t = 0; t < 8; ++t) acc0[t] += acc1[t];

    #pragma unroll
    for (int off = LPR; off < 64; off <<= 1) {
        #pragma unroll
        for (int t = 0; t < 8; ++t) acc0[t] += __shfl_down(acc0[t], off, 64);
    }

    if (lane < LPR) {
        if constexpr (EPI) {
            const float s = inv_deg[wid];
            #pragma unroll
            for (int t = 0; t < 8; ++t) acc0[t] = acc0[t] * s + bias[cg * 8 + t];
        }
        float* o = outv + (size_t)wid * F + cg * 8;
        *reinterpret_cast<float4*>(o) =
            make_float4(acc0[0], acc0[1], acc0[2], acc0[3]);
        *reinterpret_cast<float4*>(o + 4) =
            make_float4(acc0[4], acc0[5], acc0[6], acc0[7]);
    }
}

// ---------------------------------------------------------------------------
extern "C" void kernel_launch(void* const* d_in, const int* in_sizes, int n_in,
                              void* d_out, int out_size, void* d_ws, size_t ws_size,
                              hipStream_t stream)
{
    const float* x   = (const float*)d_in[0];
    const int*   src = (const int*)d_in[1];
    const int*   dst = (const int*)d_in[2];
    const float* W1  = (const float*)d_in[3];
    const float* b1  = (const float*)d_in[4];
    const float* W2  = (const float*)d_in[5];
    const float* b2  = (const float*)d_in[6];
    float* out = (float*)d_out;

    float* ws  = (float*)d_ws;
    int*   wsi = (int*)d_ws;
    int*            rowStart = wsi + OFF_ROWSTART;
    float*          invdeg   = ws  + OFF_INVDEG;
    int*            H        = wsi + OFF_H;
    int*            LOFS     = wsi + OFF_LOFS;
    int*            csr      = wsi + OFF_CSR;
    unsigned*       tmp      = (unsigned*)(wsi + OFF_TMP);
    unsigned short* Wt1      = (unsigned short*)(wsi + OFF_WT1);
    unsigned short* Wt2      = (unsigned short*)(wsi + OFF_WT2);
    float*          scaleX   = ws  + OFF_SCALEX;
    signed char*    xq       = (signed char*)(wsi + OFF_XQ);
    unsigned short* y2h      = (unsigned short*)(wsi + OFF_Y2H);

    // 1) partA + int8 quantize + W prep
    setup_kernel<<<ABLOCKS + NB_CAST + NB_PREP, 256, 0, stream>>>(
        src, dst, tmp, H, LOFS, x, xq, scaleX, W1, W2, Wt1, Wt2);

    // 2) CSR finalize per bucket
    partB_kernel<<<NBUCKETS, 256, 0, stream>>>(
        tmp, H, LOFS, csr, rowStart, invdeg, NNODES);

    // 3) fused gather(int8) + GEMM1 + GEMM2 -> y2h
    gat_gemm_kernel<<<(NNODES + 63) / 64, 256, 0, stream>>>(
        (const charv16*)xq, scaleX, csr, rowStart, invdeg,
        Wt1, b1, Wt2, y2h, NNODES);

    // 4) layer-2 aggregate + scale + bias -> out
    gather_bf16_kernel<64, true><<<(NNODES + 3) / 4, 256, 0, stream>>>(
        (const ushortv8*)y2h, csr, rowStart, invdeg, b2, out, NNODES);
}

// Round 20
// 123.238 us; speedup vs baseline: 1.4696x; 1.2125x over previous
//
#include <hip/hip_runtime.h>

// GCN 2-layer, CSR-gather formulation, bf16 intermediates + fused MFMA GEMMs.
// === r20: exact revert to r13 (best measured: 123.1us) ===
// r14 (32B/lane gather): +19us — broke coalescing. r15 (DEPTH=4): null.
// r16 (int8 gather): null — gathers byte-insensitive. r19 (gather+GEMM fused):
// +25us — fusion cut gather grid 16x (782 blocks, 24% occ) and starved the
// latency-bound gather of TLP. Attribution (r17/r18): kernels ~92us (gathers
// 47us at a latency-structure floor), gaps ~15us, fixed replay ~17us.
// 5 launches:
//   setup  : [partA: per-WG bucket partition of edges] + [cast x->bf16] +
//            [prep: W1,W2 -> bf16 W^T]                    (block-range split)
//   partB  : per bucket: inline bucket-base scan; deg -> rowStart/inv_deg;
//            scatter src into csr window
//   gather<128> : aggH = bf16(gather_sum(xh))             [fp32 accum]
//   mfma_fused  : h = relu((aggH*inv)@W1+b1) in LDS; y2h = bf16(h@W2)
//   gather<64>  : out = gather_sum(y2h)*inv + b2

constexpr int NNODES = 50000;
constexpr int NEDGES = 800000;
constexpr int NBUCKETS = (NNODES + 255) / 256;        // 196
constexpr int ABLOCKS = 200;                          // partA workgroups
constexpr int PER = (NEDGES + ABLOCKS - 1) / ABLOCKS; // 4000 edges per WG
constexpr int NB_CAST = NNODES * 128 / 8 / 256;       // 3125
constexpr int NB_PREP = (128 * 128 + 64 * 128 + 255) / 256;  // 96

// ---- workspace layout, constexpr cumulative chain (units: 4B words) -------
constexpr size_t SZ_ROWSTART = 50048;                 // needs 50001
constexpr size_t SZ_INVDEG   = 50048;
constexpr size_t SZ_H        = (size_t)ABLOCKS * 256; // 51200
constexpr size_t SZ_LOFS     = (size_t)ABLOCKS * 256;
constexpr size_t SZ_CSR      = NEDGES;
constexpr size_t SZ_TMP      = NEDGES;
constexpr size_t SZ_WT1      = 128 * 128 / 2;         // bf16 -> words
constexpr size_t SZ_WT2      = 64 * 128 / 2;
constexpr size_t SZ_XH       = (size_t)NNODES * 128 / 2;  // 3,200,000
constexpr size_t SZ_AGGH     = (size_t)NNODES * 128 / 2;  // 3,200,000
constexpr size_t SZ_Y2H      = (size_t)NNODES * 64 / 2;

constexpr size_t OFF_ROWSTART = 0;
constexpr size_t OFF_INVDEG   = OFF_ROWSTART + SZ_ROWSTART;
constexpr size_t OFF_H        = OFF_INVDEG   + SZ_INVDEG;
constexpr size_t OFF_LOFS     = OFF_H        + SZ_H;
constexpr size_t OFF_CSR      = OFF_LOFS     + SZ_LOFS;
constexpr size_t OFF_TMP      = OFF_CSR      + SZ_CSR;
constexpr size_t OFF_WT1      = OFF_TMP      + SZ_TMP;
constexpr size_t OFF_WT2      = OFF_WT1      + SZ_WT1;
constexpr size_t OFF_XH       = OFF_WT2      + SZ_WT2;
constexpr size_t OFF_AGGH     = OFF_XH       + SZ_XH;
constexpr size_t OFF_Y2H      = OFF_AGGH     + SZ_AGGH;
constexpr size_t WS_WORDS     = OFF_Y2H      + SZ_Y2H;   // 9,014,784 = 36.1 MB
static_assert(WS_WORDS < 11452800, "exceeds r7-proven workspace size");

typedef unsigned short ushortv8 __attribute__((ext_vector_type(8)));
typedef short bf16x8 __attribute__((ext_vector_type(8)));
typedef float f32x4 __attribute__((ext_vector_type(4)));

static __device__ __forceinline__ unsigned short f2bf(float f) {
    unsigned u = __float_as_uint(f);
    u += 0x7fff + ((u >> 16) & 1);  // round-to-nearest-even
    return (unsigned short)(u >> 16);
}
static __device__ __forceinline__ float bf2f(unsigned short h) {
    return __uint_as_float((unsigned)h << 16);
}

// ---------------------------------------------------------------------------
// setup: blocks [0,ABLOCKS) partA; [ABLOCKS, +NB_CAST) cast; rest prep.
// ---------------------------------------------------------------------------
__global__ __launch_bounds__(256) void setup_kernel(
    const int* __restrict__ src, const int* __restrict__ dst,
    unsigned* __restrict__ tmp, int* __restrict__ H, int* __restrict__ LOFS,
    const float* __restrict__ x, ushortv8* __restrict__ xh,
    const float* __restrict__ W1, const float* __restrict__ W2,
    unsigned short* __restrict__ Wt1, unsigned short* __restrict__ Wt2)
{
    const int blk = blockIdx.x;
    const int t = threadIdx.x;
    if (blk < ABLOCKS) {
        // ----- partA -----
        __shared__ int cnt[256];
        __shared__ int ofs[256];
        __shared__ int cur[256];
        cnt[t] = 0;
        __syncthreads();
        const int lo = blk * PER;
        const int hi = min(lo + PER, NEDGES);
        for (int i = lo + t; i < hi; i += 256)
            atomicAdd(&cnt[dst[i] >> 8], 1);
        __syncthreads();
        ofs[t] = cnt[t];
        __syncthreads();
        #pragma unroll
        for (int off = 1; off < 256; off <<= 1) {
            const int o = (t >= off) ? ofs[t - off] : 0;
            __syncthreads();
            ofs[t] += o;
            __syncthreads();
        }
        const int excl = ofs[t] - cnt[t];
        cur[t] = excl;
        H[blk * 256 + t] = cnt[t];
        LOFS[blk * 256 + t] = excl;
        __syncthreads();
        for (int i = lo + t; i < hi; i += 256) {
            const int d = dst[i];
            const unsigned pk = ((unsigned)src[i] << 8) | (unsigned)(d & 255);
            const int pos = lo + atomicAdd(&cur[d >> 8], 1);
            tmp[pos] = pk;
        }
    } else if (blk < ABLOCKS + NB_CAST) {
        // ----- cast x -> bf16, 8 elems/thread -----
        const int i = (blk - ABLOCKS) * 256 + t;  // < 800000 exactly
        const float4* p = reinterpret_cast<const float4*>(x) + (size_t)i * 2;
        const float4 a = p[0], b = p[1];
        ushortv8 v;
        v[0] = f2bf(a.x); v[1] = f2bf(a.y); v[2] = f2bf(a.z); v[3] = f2bf(a.w);
        v[4] = f2bf(b.x); v[5] = f2bf(b.y); v[6] = f2bf(b.z); v[7] = f2bf(b.w);
        xh[i] = v;
    } else {
        // ----- prep: Wt[n][k] = bf16(W[k][n]) -----
        const int i = (blk - ABLOCKS - NB_CAST) * 256 + t;
        if (i < 128 * 128) {
            const int n = i >> 7, k = i & 127;
            Wt1[i] = f2bf(W1[k * 128 + n]);
        } else if (i < 128 * 128 + 64 * 128) {
            const int j = i - 128 * 128;
            const int n = j >> 7, k = j & 127;
            Wt2[j] = f2bf(W2[k * 64 + n]);
        }
    }
}

// ---------------------------------------------------------------------------
// partB: one WG per bucket b. Inline bucket base (column-sum scan of H);
// run-prefix scan; pass1 per-node degree -> rowStart/inv_deg; pass2 scatter.
// ---------------------------------------------------------------------------
__global__ __launch_bounds__(256) void partB_kernel(
    const unsigned* __restrict__ tmp, const int* __restrict__ H,
    const int* __restrict__ LOFS, int* __restrict__ csr,
    int* __restrict__ rowStart, float* __restrict__ inv_deg, int nNodes)
{
    __shared__ int cs[256];    // column sums (bucket totals)
    __shared__ int s[256];     // scan scratch
    __shared__ int epfx[256];  // exclusive run prefix for this bucket
    __shared__ int base[256];  // run base addr in tmp
    __shared__ int cnt[256];
    __shared__ int fill[256];
    const int b = blockIdx.x;
    const int t = threadIdx.x;

    int sum = 0;
    for (int w = 0; w < ABLOCKS; ++w) sum += H[w * 256 + t];
    cs[t] = sum;
    s[t] = sum;
    __syncthreads();
    #pragma unroll
    for (int off = 1; off < 256; off <<= 1) {
        const int o = (t >= off) ? s[t - off] : 0;
        __syncthreads();
        s[t] += o;
        __syncthreads();
    }
    const int gbase = s[b] - cs[b];  // exclusive prefix at bucket b
    const int total = cs[b];
    __syncthreads();  // all threads read s[b] before s is reused

    const int hv = (t < ABLOCKS) ? H[t * 256 + b] : 0;
    s[t] = hv;
    if (t < ABLOCKS) base[t] = t * PER + LOFS[t * 256 + b];
    cnt[t] = 0;
    __syncthreads();
    #pragma unroll
    for (int off = 1; off < 256; off <<= 1) {
        const int o = (t >= off) ? s[t - off] : 0;
        __syncthreads();
        s[t] += o;
        __syncthreads();
    }
    epfx[t] = s[t] - hv;
    __syncthreads();

    // pass 1: per-node degree
    for (int j = t; j < total; j += 256) {
        int loW = 0, hiW = ABLOCKS;
        while (hiW - loW > 1) {
            const int mid = (loW + hiW) >> 1;
            if (epfx[mid] <= j) loW = mid; else hiW = mid;
        }
        const unsigned p = tmp[base[loW] + (j - epfx[loW])];
        atomicAdd(&cnt[p & 255u], 1);
    }
    __syncthreads();
    s[t] = cnt[t];
    __syncthreads();
    #pragma unroll
    for (int off = 1; off < 256; off <<= 1) {
        const int o = (t >= off) ? s[t - off] : 0;
        __syncthreads();
        s[t] += o;
        __syncthreads();
    }
    const int excl = gbase + s[t] - cnt[t];
    const int node = b * 256 + t;
    if (node < nNodes) {
        rowStart[node] = excl;
        inv_deg[node] = 1.0f / fmaxf((float)cnt[t], 1.0f);
    }
    if (b == 0 && t == 0) rowStart[nNodes] = NEDGES;
    fill[t] = excl;
    __syncthreads();

    // pass 2: scatter
    for (int j = t; j < total; j += 256) {
        int loW = 0, hiW = ABLOCKS;
        while (hiW - loW > 1) {
            const int mid = (loW + hiW) >> 1;
            if (epfx[mid] <= j) loW = mid; else hiW = mid;
        }
        const unsigned p = tmp[base[loW] + (j - epfx[loW])];
        const int pos = atomicAdd(&fill[p & 255u], 1);
        csr[pos] = (int)(p >> 8);
    }
}

// ---------------------------------------------------------------------------
// bf16-row gather-aggregate (r13-proven shape): one wave per dst node;
// 64 lanes = EPW edge-slots x LPR 8-elem column groups (16B/lane, fully
// coalesced). fp32 accumulate, 2-deep edge unroll, shuffle-reduce,
// coalesced row write. EPI: fuse *inv_deg + bias. OBF16: emit bf16 row.
// ---------------------------------------------------------------------------
template<int F, bool EPI, bool OBF16>
__global__ __launch_bounds__(256) void gather_bf16_kernel(
    const ushortv8* __restrict__ feat, const int* __restrict__ csr,
    const int* __restrict__ rowStart, const float* __restrict__ inv_deg,
    const float* __restrict__ bias, void* __restrict__ outv, int nNodes)
{
    constexpr int LPR = F / 8;     // lanes per row: 16 (F=128) / 8 (F=64)
    constexpr int EPW = 64 / LPR;  // parallel edges per wave: 4 / 8
    const int wid = (blockIdx.x * 256 + threadIdx.x) >> 6;
    if (wid >= nNodes) return;
    const int lane = threadIdx.x & 63;
    const int eslot = lane / LPR;
    const int cg = lane % LPR;
    const int rs = rowStart[wid];
    const int re = rowStart[wid + 1];

    float acc0[8] = {}, acc1[8] = {};
    int j = rs + eslot;
    for (; j + EPW < re; j += 2 * EPW) {
        const int s0 = csr[j];
        const int s1 = csr[j + EPW];
        const ushortv8 v0 = feat[(size_t)s0 * LPR + cg];
        const ushortv8 v1 = feat[(size_t)s1 * LPR + cg];
        #pragma unroll
        for (int t = 0; t < 8; ++t) acc0[t] += bf2f(v0[t]);
        #pragma unroll
        for (int t = 0; t < 8; ++t) acc1[t] += bf2f(v1[t]);
    }
    if (j < re) {
        const int s0 = csr[j];
        const ushortv8 v0 = feat[(size_t)s0 * LPR + cg];
        #pragma unroll
        for (int t = 0; t < 8; ++t) acc0[t] += bf2f(v0[t]);
    }
    #pragma unroll
    for (int t = 0; t < 8; ++t) acc0[t] += acc1[t];

    #pragma unroll
    for (int off = LPR; off < 64; off <<= 1) {
        #pragma unroll
        for (int t = 0; t < 8; ++t) acc0[t] += __shfl_down(acc0[t], off, 64);
    }

    if (lane < LPR) {
        if constexpr (EPI) {
            const float s = inv_deg[wid];
            #pragma unroll
            for (int t = 0; t < 8; ++t) acc0[t] = acc0[t] * s + bias[cg * 8 + t];
        }
        if constexpr (OBF16) {
            ushortv8 ov;
            #pragma unroll
            for (int t = 0; t < 8; ++t) ov[t] = f2bf(acc0[t]);
            *reinterpret_cast<ushortv8*>(
                (unsigned short*)outv + (size_t)wid * F + cg * 8) = ov;
        } else {
            float* o = (float*)outv + (size_t)wid * F + cg * 8;
            *reinterpret_cast<float4*>(o) =
                make_float4(acc0[0], acc0[1], acc0[2], acc0[3]);
            *reinterpret_cast<float4*>(o + 4) =
                make_float4(acc0[4], acc0[5], acc0[6], acc0[7]);
        }
    }
}

// ---------------------------------------------------------------------------
// Fused MFMA GEMMs, K=128, block = 4 waves = 64 rows (r13-proven):
//   h = relu((A*inv_deg)@Wt1^T + b1)   -> bf16, kept in LDS (la)
//   y2h = bf16(h@Wt2^T)                -> global
// Barriers: after staging; between epi1 ds_writes and GEMM2 ds_reads (no data
// dep -> scheduler may reorder otherwise); after GEMM2 before la reuse;
// before cooperative store.
// ---------------------------------------------------------------------------
__global__ __launch_bounds__(256) void mfma_fused_kernel(
    const ushortv8* __restrict__ A,      // aggH bf16 [nrows][16 chunks]
    const float* __restrict__ inv_deg,
    const ushortv8* __restrict__ Wt1,    // bf16 [128][16 chunks]
    const float* __restrict__ b1,
    const ushortv8* __restrict__ Wt2,    // bf16 [64][16 chunks]
    unsigned short* __restrict__ y2h,    // bf16 [nrows][64]
    int nrows)
{
    constexpr int LDK = 136;  // +8 bf16 pad
    __shared__ alignas(16) unsigned short lwt1[128][LDK];
    __shared__ alignas(16) unsigned short lwt2[64][LDK];
    __shared__ alignas(16) unsigned short la[64][LDK];

    const int row0 = blockIdx.x * 64;
    const int t = threadIdx.x;

    for (int i = t; i < 128 * 16; i += 256) {
        const int r = i >> 4, c = i & 15;
        *reinterpret_cast<ushortv8*>(&lwt1[r][c * 8]) = Wt1[i];
    }
    for (int i = t; i < 64 * 16; i += 256) {
        const int r = i >> 4, c = i & 15;
        *reinterpret_cast<ushortv8*>(&lwt2[r][c * 8]) = Wt2[i];
    }
    for (int i = t; i < 64 * 16; i += 256) {
        const int r = i >> 4, c = i & 15;
        const int row = row0 + r;
        ushortv8 v = {};
        if (row < nrows) {
            v = A[(size_t)row * 16 + c];
            const float s = inv_deg[row];
            #pragma unroll
            for (int jj = 0; jj < 8; ++jj) v[jj] = f2bf(bf2f(v[jj]) * s);
        }
        *reinterpret_cast<ushortv8*>(&la[r][c * 8]) = v;
    }
    __syncthreads();

    const int wave = t >> 6, lane = t & 63;
    const int m = lane & 15, kg = lane >> 4;  // k-group 0..3

    // GEMM1: 64x128 = (64x128) @ (128x128)
    f32x4 acc1[8] = {};
    #pragma unroll
    for (int kk = 0; kk < 4; ++kk) {
        const bf16x8 af =
            *reinterpret_cast<const bf16x8*>(&la[wave * 16 + m][kk * 32 + kg * 8]);
        #pragma unroll
        for (int n = 0; n < 8; ++n) {
            const bf16x8 bf =
                *reinterpret_cast<const bf16x8*>(&lwt1[n * 16 + m][kk * 32 + kg * 8]);
            acc1[n] = __builtin_amdgcn_mfma_f32_16x16x32_bf16(af, bf, acc1[n], 0, 0, 0);
        }
    }
    // epilogue1: h = bf16(relu(acc+b1)) into own la rows
    #pragma unroll
    for (int n = 0; n < 8; ++n) {
        const float bv = b1[n * 16 + m];
        #pragma unroll
        for (int q = 0; q < 4; ++q) {
            const int r = wave * 16 + kg * 4 + q;
            la[r][n * 16 + m] = f2bf(fmaxf(acc1[n][q] + bv, 0.f));
        }
    }
    __syncthreads();  // order h ds_writes before GEMM2 ds_reads

    // GEMM2: 64x64 = (64x128) @ (128x64)
    f32x4 acc2[4] = {};
    #pragma unroll
    for (int kk = 0; kk < 4; ++kk) {
        const bf16x8 af =
            *reinterpret_cast<const bf16x8*>(&la[wave * 16 + m][kk * 32 + kg * 8]);
        #pragma unroll
        for (int n = 0; n < 4; ++n) {
            const bf16x8 bf =
                *reinterpret_cast<const bf16x8*>(&lwt2[n * 16 + m][kk * 32 + kg * 8]);
            acc2[n] = __builtin_amdgcn_mfma_f32_16x16x32_bf16(af, bf, acc2[n], 0, 0, 0);
        }
    }
    __syncthreads();  // all GEMM2 reads of la complete before epilogue2 rewrites it
    // epilogue2: stage y2h bf16 into own la rows (cols 0..63)
    #pragma unroll
    for (int n = 0; n < 4; ++n) {
        #pragma unroll
        for (int q = 0; q < 4; ++q) {
            const int r = wave * 16 + kg * 4 + q;
            la[r][n * 16 + m] = f2bf(acc2[n][q]);
        }
    }
    __syncthreads();
    for (int i = t; i < 64 * 8; i += 256) {
        const int r = i >> 3, c = i & 7;
        const int row = row0 + r;
        if (row < nrows)
            *reinterpret_cast<ushortv8*>(&y2h[(size_t)row * 64 + c * 8]) =
                *reinterpret_cast<const ushortv8*>(&la[r][c * 8]);
    }
}

// ---------------------------------------------------------------------------
extern "C" void kernel_launch(void* const* d_in, const int* in_sizes, int n_in,
                              void* d_out, int out_size, void* d_ws, size_t ws_size,
                              hipStream_t stream)
{
    const float* x   = (const float*)d_in[0];
    const int*   src = (const int*)d_in[1];
    const int*   dst = (const int*)d_in[2];
    const float* W1  = (const float*)d_in[3];
    const float* b1  = (const float*)d_in[4];
    const float* W2  = (const float*)d_in[5];
    const float* b2  = (const float*)d_in[6];
    float* out = (float*)d_out;

    float* ws  = (float*)d_ws;
    int*   wsi = (int*)d_ws;
    int*            rowStart = wsi + OFF_ROWSTART;
    float*          invdeg   = ws  + OFF_INVDEG;
    int*            H        = wsi + OFF_H;
    int*            LOFS     = wsi + OFF_LOFS;
    int*            csr      = wsi + OFF_CSR;
    unsigned*       tmp      = (unsigned*)(wsi + OFF_TMP);
    unsigned short* Wt1      = (unsigned short*)(wsi + OFF_WT1);
    unsigned short* Wt2      = (unsigned short*)(wsi + OFF_WT2);
    ushortv8*       xh       = (ushortv8*)(wsi + OFF_XH);
    ushortv8*       aggH     = (ushortv8*)(wsi + OFF_AGGH);
    unsigned short* y2h      = (unsigned short*)(wsi + OFF_Y2H);

    // 1) partA + cast + prep (independent work, block-range split)
    setup_kernel<<<ABLOCKS + NB_CAST + NB_PREP, 256, 0, stream>>>(
        src, dst, tmp, H, LOFS, x, xh, W1, W2, Wt1, Wt2);

    // 2) CSR finalize per bucket (inline bucket-base scan)
    partB_kernel<<<NBUCKETS, 256, 0, stream>>>(
        tmp, H, LOFS, csr, rowStart, invdeg, NNODES);

    // 3) layer-1 aggregate -> bf16 aggH
    gather_bf16_kernel<128, false, true><<<(NNODES + 3) / 4, 256, 0, stream>>>(
        xh, csr, rowStart, nullptr, nullptr, aggH, NNODES);

    // 4) fused GEMM1(scale+bias+relu) + GEMM2 -> y2h
    mfma_fused_kernel<<<(NNODES + 63) / 64, 256, 0, stream>>>(
        aggH, invdeg, (const ushortv8*)Wt1, b1, (const ushortv8*)Wt2,
        y2h, NNODES);

    // 5) layer-2 aggregate + scale + bias -> out (fp32)
    gather_bf16_kernel<64, true, false><<<(NNODES + 3) / 4, 256, 0, stream>>>(
        (const ushortv8*)y2h, csr, rowStart, invdeg, b2, out, NNODES);
}